// Round 7
// baseline (14767.488 us; speedup 1.0000x reference)
//
#include <hip/hip_runtime.h>
#include <hip/hip_bf16.h>
#include <stdint.h>

// ---------------------------------------------------------------------------
// TensorizedGRU: m[b,l] = sum_{j,k} s[b,j] x[b,k] W[l,j,k]  (l in [0,256): W1||W2)
// R7: attack L2-W-bandwidth bound (every prior round: MFMA busy ~58us, rest
// stalls on W reads from L2):
//  - 256m x 128n block tile, 1024 threads (16 waves = 4 wm x 4 wn, each
//    64m x 32n). Same-wn waves read identical W lines -> L1 hits -> L2 W
//    traffic 2.1GB -> 0.5GB. Grid 256 = 1 block/CU, 4 waves/SIMD.
//  - K-loop chunk order rotated per block (rot = 4nt+8mt): de-lockstep the
//    same-address streams across CUs -> spread over L2 channels.
//  - ks = bx&7 pins split-K slice per XCD (4MB W slice == its L2).
//  - amdgpu_waves_per_eu(4,4): stop the compiler from squeezing VGPRs for
//    unusable occupancy (R6 pathology). Explicit depth-1 ping-pong B-frags.
//  - Regular stores only (R5 nt-store divergence).
// ws layout:
//   Wt   bf16 [256][65536]  @ 0          (33,554,432 B)
//   x_bf bf16 [4096][256]   @ 32MiB+2MiB ( 2,097,152 B)
//   Mpart f32 [8][4096][256]@ +2MiB      (33,554,432 B)
// ---------------------------------------------------------------------------

typedef short bf8 __attribute__((ext_vector_type(8)));   // 8 bf16 = 4 VGPRs
typedef float f32x4 __attribute__((ext_vector_type(4)));

static constexpr size_t WT_OFF  = 0;
static constexpr size_t XBF_OFF = 33554432 + 2097152;
static constexpr size_t MP_OFF  = XBF_OFF + 2097152;

// round-to-nearest-even f32 -> bf16 (finite inputs only)
__device__ __forceinline__ unsigned f2bf(float f) {
    unsigned u = __builtin_bit_cast(unsigned, f);
    return (u + 0x7fffu + ((u >> 16) & 1u)) >> 16;
}
__device__ __forceinline__ unsigned pack2bf(float a, float b) {
    return f2bf(a) | (f2bf(b) << 16);
}

// ---------------- prep: W f32->bf16 (blocks 0..8191) + x (blocks 8192..9215)
__global__ void prep_wx(const float* __restrict__ W1, const float* __restrict__ W2,
                        const float* __restrict__ in0, const float* __restrict__ in1,
                        unsigned* __restrict__ Wt, unsigned* __restrict__ x_bf) {
    int bx = blockIdx.x;
    if (bx < 8192) {
        unsigned u = bx * 256 + threadIdx.x;          // 2,097,152 units of 8 elems
        size_t e = (size_t)u * 8;
        unsigned n = (unsigned)(e >> 16);
        unsigned k = (unsigned)(e & 65535u);
        const float* src = (n < 128 ? W1 + ((size_t)n << 16)
                                    : W2 + ((size_t)(n - 128) << 16)) + k;
        float4 a = ((const float4*)src)[0];
        float4 b = ((const float4*)src)[1];
        uint4 o;
        o.x = pack2bf(a.x, a.y); o.y = pack2bf(a.z, a.w);
        o.z = pack2bf(b.x, b.y); o.w = pack2bf(b.z, b.w);
        ((uint4*)Wt)[u] = o;
    } else {
        unsigned v = (bx - 8192) * 256 + threadIdx.x; // 262,144 units of 4 elems
        unsigned b = v >> 6;
        unsigned j4 = (v & 63u) * 4u;
        const float* src = (j4 < 128) ? (in0 + (size_t)b * 128 + j4)
                                      : (in1 + (size_t)b * 128 + (j4 - 128));
        float4 a = *(const float4*)src;
        uint2 o;
        o.x = pack2bf(a.x, a.y);
        o.y = pack2bf(a.z, a.w);
        ((uint2*)x_bf)[v] = o;
    }
}

// ---------------- main GEMM: 256x128 tile, split-K=8, barrier-free ----------
// grid 256: ks = bx&7 (XCD-pinned), nt = (bx>>3)&1, mt = bx>>4 (0..15).
// block 1024 = 16 waves; wave (wm,wn) owns rows [wm*64,+64), cols [wn*32,+32).
__global__ void
__attribute__((amdgpu_flat_work_group_size(1024, 1024)))
__attribute__((amdgpu_waves_per_eu(4, 4)))
gemm_p(const __hip_bfloat16* __restrict__ Wt,
       const float* __restrict__ st0, const float* __restrict__ st1,
       const __hip_bfloat16* __restrict__ x_bf,
       float* __restrict__ Mpart) {
    const int bx = blockIdx.x;
    const int ks = bx & 7;                  // split-K slice, pinned per XCD
    const int nt = (bx >> 3) & 1;
    const int mt = bx >> 4;
    const int b0 = mt << 8, n0 = nt << 7;
    const int tid  = threadIdx.x;
    const int lane = tid & 63, wave = tid >> 6;
    const int wm = wave & 3, wn = wave >> 2;
    const int l15 = lane & 15, l4 = lane >> 4;

    // s tile: [32 j][260 r] f32 (pad 256->260, 16B-aligned rows)
    __shared__ __align__(16) float Sl[32 * 260];
    for (int idx = tid; idx < 8192; idx += 1024) {
        int r = idx >> 5, j = idx & 31;
        int jg = ks * 32 + j;
        float v = (jg < 128) ? st0[(size_t)(b0 + r) * 128 + jg]
                             : st1[(size_t)(b0 + r) * 128 + (jg - 128)];
        Sl[j * 260 + r] = v;
    }
    __syncthreads();                        // the ONLY barrier

    // B-frag base: lane l reads Wt[n0+wn*32+nf*16+l15][jk + kst*32 + l4*8 ..+8]
    const __hip_bfloat16* rb = Wt + ((size_t)(n0 + wn * 32 + l15) << 16) + l4 * 8;
    const float* sBw = Sl + wm * 64 + l4 * 4;   // + j*260 + mf*16

    f32x4 racc[4][2];
    #pragma unroll
    for (int mf = 0; mf < 4; ++mf)
        #pragma unroll
        for (int nf = 0; nf < 2; ++nf)
            racc[mf][nf] = (f32x4){0.f, 0.f, 0.f, 0.f};
    const f32x4 zacc = (f32x4){0.f, 0.f, 0.f, 0.f};

    // chunk c: q = c>>5 (x-quadrant), j = c&31 (local j within ks slice)
    auto jkof = [&](int c) { return (ks * 32 + (c & 31)) * 256 + (c >> 5) * 64; };

    const int rot = (bx >> 3) << 2;         // 4*nt + 8*mt: stagger phase
    bf8 a[4][2];                            // x A-frags for current quadrant
    bf8 buf[2][2][2];                       // [ping][nf][kst]

    // prime: A-frags for starting quadrant + B-frags for first chunk
    {
        const int c0 = rot & 127, q0 = c0 >> 5;
        const __hip_bfloat16* xb = x_bf + q0 * 64 + l4 * 8;
        #pragma unroll
        for (int mf = 0; mf < 4; ++mf)
            #pragma unroll
            for (int kst = 0; kst < 2; ++kst)
                a[mf][kst] = *(const bf8*)(xb + (size_t)(b0 + wm * 64 + mf * 16 + l15) * 256 + kst * 32);
        const int jk0 = jkof(c0);
        #pragma unroll
        for (int nf = 0; nf < 2; ++nf)
            #pragma unroll
            for (int kst = 0; kst < 2; ++kst)
                buf[0][nf][kst] = *(const bf8*)(rb + ((size_t)nf << 20) + jk0 + kst * 32);
    }

    for (int cc = rot; cc < rot + 128; ++cc) {
        const int pp = cc & 1;
        const int c = cc & 127;
        const int q = c >> 5, j = c & 31;
        // quadrant change (cc crosses multiple of 32, except the primed start)
        if ((cc & 31) == 0 && cc != rot) {
            const __hip_bfloat16* xb = x_bf + q * 64 + l4 * 8;
            #pragma unroll
            for (int mf = 0; mf < 4; ++mf)
                #pragma unroll
                for (int kst = 0; kst < 2; ++kst)
                    a[mf][kst] = *(const bf8*)(xb + (size_t)(b0 + wm * 64 + mf * 16 + l15) * 256 + kst * 32);
        }
        // prefetch next chunk's B-frags (last-iter wrap harmless)
        {
            const int jk1 = jkof((cc + 1) & 127);
            #pragma unroll
            for (int nf = 0; nf < 2; ++nf)
                #pragma unroll
                for (int kst = 0; kst < 2; ++kst)
                    buf[pp ^ 1][nf][kst] = *(const bf8*)(rb + ((size_t)nf << 20) + jk1 + kst * 32);
        }
        // s broadcast values for this j
        f32x4 sv[4];
        #pragma unroll
        for (int mf = 0; mf < 4; ++mf)
            sv[mf] = *(const f32x4*)(sBw + j * 260 + mf * 16);
        // 16 MFMA + f32 scale-accumulate
        #pragma unroll
        for (int nf = 0; nf < 2; ++nf) {
            bf8 bf0 = buf[pp][nf][0];
            bf8 bf1 = buf[pp][nf][1];
            #pragma unroll
            for (int mf = 0; mf < 4; ++mf) {
                f32x4 m0 = __builtin_amdgcn_mfma_f32_16x16x32_bf16(a[mf][0], bf0, zacc, 0, 0, 0);
                m0 = __builtin_amdgcn_mfma_f32_16x16x32_bf16(a[mf][1], bf1, m0, 0, 0, 0);
                racc[mf][nf] += sv[mf] * m0;
            }
        }
    }

    // split-K partial stores (regular stores: producer->consumer coherence)
    float* mp = Mpart + ((size_t)ks << 20);
    #pragma unroll
    for (int mf = 0; mf < 4; ++mf)
        #pragma unroll
        for (int nf = 0; nf < 2; ++nf) {
            int b = b0 + wm * 64 + mf * 16 + l4 * 4;
            int n = n0 + wn * 32 + nf * 16 + l15;
            #pragma unroll
            for (int r = 0; r < 4; ++r)
                mp[(size_t)(b + r) * 256 + n] = racc[mf][nf][r];
        }
}

// ---------------- epilogue: reduce split-K, s@W3, activations, blend --------
__global__ void epilogue(const float* __restrict__ st0, const float* __restrict__ st1,
                         const float* __restrict__ b1, const float* __restrict__ b2,
                         const float* __restrict__ W3, const float* __restrict__ Mpart,
                         float* __restrict__ out) {
    const int tid = threadIdx.x;
    const int h = tid & 127, rg = tid >> 7;          // rg in {0,1}
    const int bbase = blockIdx.x * 8;                // 8 rows per block
    __shared__ float srow[8][256];
    #pragma unroll
    for (int i = 0; i < 8; ++i) {
        int idx = i * 256 + tid;
        int r = idx >> 8, j = idx & 255;
        float v = (j < 128) ? st0[(size_t)(bbase + r) * 128 + j]
                            : st1[(size_t)(bbase + r) * 128 + (j - 128)];
        srow[r][j] = v;
    }
    __syncthreads();
    float acc0 = 0.f, acc1 = 0.f, acc2 = 0.f, acc3 = 0.f;
    for (int j = 0; j < 256; ++j) {
        float w = W3[j * 128 + h];
        acc0 += srow[rg][j] * w;
        acc1 += srow[rg + 2][j] * w;
        acc2 += srow[rg + 4][j] * w;
        acc3 += srow[rg + 6][j] * w;
    }
    float accs[4] = {acc0, acc1, acc2, acc3};
    float bb1 = b1[h], bb2 = b2[h];
    #pragma unroll
    for (int i = 0; i < 4; ++i) {
        int b = bbase + rg + i * 2;
        float m1 = 0.f, m2 = 0.f;
        #pragma unroll
        for (int k = 0; k < 8; ++k) {
            m1 += Mpart[((size_t)k << 20) + (size_t)b * 256 + h];
            m2 += Mpart[((size_t)k << 20) + (size_t)b * 256 + 128 + h];
        }
        float u = 1.0f / (1.0f + expf(-(m2 + bb2)));
        float t = tanhf(m1 + bb1);
        out[(size_t)b * 128 + h] = u * t + (1.0f - u) * accs[i];
    }
}

extern "C" void kernel_launch(void* const* d_in, const int* in_sizes, int n_in,
                              void* d_out, int out_size, void* d_ws, size_t ws_size,
                              hipStream_t stream) {
    const float* in0 = (const float*)d_in[0];
    const float* in1 = (const float*)d_in[1];
    const float* st0 = (const float*)d_in[2];
    const float* st1 = (const float*)d_in[3];
    const float* W1  = (const float*)d_in[4];
    const float* b1  = (const float*)d_in[5];
    const float* W2  = (const float*)d_in[6];
    const float* b2  = (const float*)d_in[7];
    const float* W3  = (const float*)d_in[8];
    float* out = (float*)d_out;
    char* ws = (char*)d_ws;

    __hip_bfloat16* Wt   = (__hip_bfloat16*)(ws + WT_OFF);
    unsigned*       x_bf = (unsigned*)(ws + XBF_OFF);
    float*          Mp   = (float*)(ws + MP_OFF);

    prep_wx<<<9216, 256, 0, stream>>>(W1, W2, in0, in1, (unsigned*)Wt, x_bf);
    gemm_p<<<256, 1024, 0, stream>>>(Wt, st0, st1, (const __hip_bfloat16*)x_bf, Mp);
    epilogue<<<512, 256, 0, stream>>>(st0, st1, b1, b2, W3, Mp, out);
}

// Round 8
// 266.119 us; speedup vs baseline: 55.4921x; 55.4921x over previous
//
#include <hip/hip_runtime.h>
#include <hip/hip_bf16.h>
#include <stdint.h>

// ---------------------------------------------------------------------------
// TensorizedGRU: m[b,l] = sum_{j,k} s[b,j] x[b,k] W[l,j,k]  (l in [0,256): W1||W2)
// R8 = R4 (160us, no spills) + fragment-ordered Wt layout:
//  - Wt stored as MFMA B-fragments: for each (n16 = n-group of 16,
//    kchunk = k-group of 64, kst = k-half of 32), a 1KB block holding the
//    exact bytes wave-lane l reads at offset l*16. B-frag load becomes ONE
//    contiguous coalesced 1KB global_load_dwordx4 (was a 16-line gather with
//    128KB lane stride). Consecutive K-chunks stream sequentially.
//  - 64...128m x 128n tile as R4: wave w = all 128 m-rows x 32 n-cols; grid 512
//    (2 blocks/CU), __launch_bounds__(256,2), VGPR ~124 + AGPR racc.
//  - ks = bx&7 pins split-K slice per XCD; barrier-free K-loop, depth-1
//    ping-pong register prefetch; regular stores (nt-store hazard, R5).
// ws layout:
//   Wt   bf16 [256][65536]  @ 0          (33,554,432 B)  fragment-ordered
//   x_bf bf16 [4096][256]   @ 32MiB+2MiB ( 2,097,152 B)
//   Mpart f32 [8][4096][256]@ +2MiB      (33,554,432 B)
// ---------------------------------------------------------------------------

typedef short bf8 __attribute__((ext_vector_type(8)));   // 8 bf16 = 4 VGPRs
typedef float f32x4 __attribute__((ext_vector_type(4)));

static constexpr size_t WT_OFF  = 0;
static constexpr size_t XBF_OFF = 33554432 + 2097152;
static constexpr size_t MP_OFF  = XBF_OFF + 2097152;

// round-to-nearest-even f32 -> bf16 (finite inputs only)
__device__ __forceinline__ unsigned f2bf(float f) {
    unsigned u = __builtin_bit_cast(unsigned, f);
    return (u + 0x7fffu + ((u >> 16) & 1u)) >> 16;
}
__device__ __forceinline__ unsigned pack2bf(float a, float b) {
    return f2bf(a) | (f2bf(b) << 16);
}

// ---------------- prep: W f32->bf16 into FRAGMENT-ORDERED Wt + x cast -------
// Wt uint4 index for bf16 element (n, K):
//   n16=n>>4, nr=n&15, kchunk=K>>6, kin=K&63, kst=kin>>5, l4g=(kin&31)>>3
//   oi = ((n16*1024 + kchunk)*2 + kst)*64 + l4g*16 + nr
__global__ void prep_wx(const float* __restrict__ W1, const float* __restrict__ W2,
                        const float* __restrict__ in0, const float* __restrict__ in1,
                        unsigned* __restrict__ Wt, unsigned* __restrict__ x_bf) {
    int bx = blockIdx.x;
    if (bx < 8192) {
        unsigned u = bx * 256 + threadIdx.x;          // 2,097,152 units of 8 elems
        size_t e = (size_t)u * 8;
        unsigned n = (unsigned)(e >> 16);
        unsigned K = (unsigned)(e & 65535u);
        const float* src = (n < 128 ? W1 + ((size_t)n << 16)
                                    : W2 + ((size_t)(n - 128) << 16)) + K;
        float4 a = ((const float4*)src)[0];
        float4 b = ((const float4*)src)[1];
        uint4 o;
        o.x = pack2bf(a.x, a.y); o.y = pack2bf(a.z, a.w);
        o.z = pack2bf(b.x, b.y); o.w = pack2bf(b.z, b.w);
        unsigned n16 = n >> 4, nr = n & 15;
        unsigned kchunk = K >> 6, kin = K & 63u;
        unsigned kst = kin >> 5, l4g = (kin & 31u) >> 3;
        unsigned oi = ((n16 * 1024u + kchunk) * 2u + kst) * 64u + l4g * 16u + nr;
        ((uint4*)Wt)[oi] = o;
    } else {
        unsigned v = (bx - 8192) * 256 + threadIdx.x; // 262,144 units of 4 elems
        unsigned b = v >> 6;
        unsigned j4 = (v & 63u) * 4u;
        const float* src = (j4 < 128) ? (in0 + (size_t)b * 128 + j4)
                                      : (in1 + (size_t)b * 128 + (j4 - 128));
        float4 a = *(const float4*)src;
        uint2 o;
        o.x = pack2bf(a.x, a.y);
        o.y = pack2bf(a.z, a.w);
        ((uint2*)x_bf)[v] = o;
    }
}

// ---------------- main GEMM: 128x128 tile, split-K=8, barrier-free ----------
// grid 512: ks = bx&7 (XCD-pinned), nt = (bx>>3)&1, mt = bx>>4 (0..31).
// block 256 = 4 waves; wave w owns n-cols [w*32, w*32+32), all 128 m-rows.
__launch_bounds__(256, 2)
__global__ void gemm_p(const unsigned char* __restrict__ Wt,
                       const float* __restrict__ st0, const float* __restrict__ st1,
                       const __hip_bfloat16* __restrict__ x_bf,
                       float* __restrict__ Mpart) {
    const int bx = blockIdx.x;
    const int ks = bx & 7;                  // split-K slice, pinned per XCD
    const int nt = (bx >> 3) & 1;
    const int mt = bx >> 4;
    const int b0 = mt << 7, n0 = nt << 7;
    const int tid  = threadIdx.x;
    const int lane = tid & 63, wave = tid >> 6;
    const int l15 = lane & 15, l4 = lane >> 4;

    // s tile: [32 j][132 r] f32 (pad to 132 -> broadcast-clean)
    __shared__ __align__(16) float Sl[32 * 132];
    for (int idx = tid; idx < 4096; idx += 256) {
        int r = idx >> 5, j = idx & 31;
        int jg = ks * 32 + j;
        float v = (jg < 128) ? st0[(size_t)(b0 + r) * 128 + jg]
                             : st1[(size_t)(b0 + r) * 128 + (jg - 128)];
        Sl[j * 132 + r] = v;
    }
    __syncthreads();                        // the ONLY barrier

    // B-frag bases, fragment-ordered Wt:
    // n16(nf) = nt*8 + wave*2 + nf; frag addr = ((n16*1024 + kchunk)*2+kst)*1024 + lane*16
    const unsigned char* rbn[2];
    #pragma unroll
    for (int nf = 0; nf < 2; ++nf)
        rbn[nf] = Wt + ((size_t)(nt * 8 + wave * 2 + nf) << 21) + lane * 16;
    const float* sB = Sl + l4 * 4;

    f32x4 racc[8][2];
    #pragma unroll
    for (int mf = 0; mf < 8; ++mf)
        #pragma unroll
        for (int nf = 0; nf < 2; ++nf)
            racc[mf][nf] = (f32x4){0.f, 0.f, 0.f, 0.f};
    const f32x4 zacc = (f32x4){0.f, 0.f, 0.f, 0.f};

    // chunk c in [0,128): q = c>>5 (x-quadrant), j = c&31 (local j)
    // kchunk(c) = ((ks*32 + j)*4 + q); byte offset = kchunk*2048 (+ kst*1024)
    auto kof = [&](int c) { return (size_t)(((ks * 32 + (c & 31)) * 4 + (c >> 5)) * 2048); };

    bf8 buf[2][2][2];                       // [ping][nf][kst]
    #pragma unroll
    for (int nf = 0; nf < 2; ++nf)
        #pragma unroll
        for (int kst = 0; kst < 2; ++kst)
            buf[0][nf][kst] = *(const bf8*)(rbn[nf] + kof(0) + kst * 1024);

    bf8 a[8][2];                            // x A-frags, reloaded at q boundary

    #pragma unroll 2
    for (int c = 0; c < 128; ++c) {
        const int pp = c & 1;
        const int q = c >> 5, j = c & 31;
        if (j == 0) {                       // new x-quadrant: reload A-frags
            const __hip_bfloat16* xb = x_bf + q * 64 + l4 * 8;
            #pragma unroll
            for (int mf = 0; mf < 8; ++mf)
                #pragma unroll
                for (int kst = 0; kst < 2; ++kst)
                    a[mf][kst] = *(const bf8*)(xb + (size_t)(b0 + mf * 16 + l15) * 256 + kst * 32);
        }
        // prefetch next chunk's B-frags (wraps to 0 on last iter: harmless)
        {
            const size_t k1 = kof((c + 1) & 127);
            #pragma unroll
            for (int nf = 0; nf < 2; ++nf)
                #pragma unroll
                for (int kst = 0; kst < 2; ++kst)
                    buf[pp ^ 1][nf][kst] = *(const bf8*)(rbn[nf] + k1 + kst * 1024);
        }
        // s broadcast values for this j
        f32x4 sv[8];
        #pragma unroll
        for (int mf = 0; mf < 8; ++mf)
            sv[mf] = *(const f32x4*)(sB + j * 132 + mf * 16);
        // 32 MFMA + f32 scale-accumulate
        #pragma unroll
        for (int nf = 0; nf < 2; ++nf) {
            bf8 bf0 = buf[pp][nf][0];
            bf8 bf1 = buf[pp][nf][1];
            #pragma unroll
            for (int mf = 0; mf < 8; ++mf) {
                f32x4 m0 = __builtin_amdgcn_mfma_f32_16x16x32_bf16(a[mf][0], bf0, zacc, 0, 0, 0);
                m0 = __builtin_amdgcn_mfma_f32_16x16x32_bf16(a[mf][1], bf1, m0, 0, 0, 0);
                racc[mf][nf] += sv[mf] * m0;
            }
        }
    }

    // split-K partial stores (regular stores: producer->consumer coherence)
    float* mp = Mpart + ((size_t)ks << 20);
    #pragma unroll
    for (int mf = 0; mf < 8; ++mf)
        #pragma unroll
        for (int nf = 0; nf < 2; ++nf) {
            int b = b0 + mf * 16 + l4 * 4;
            int n = n0 + wave * 32 + nf * 16 + l15;
            #pragma unroll
            for (int r = 0; r < 4; ++r)
                mp[(size_t)(b + r) * 256 + n] = racc[mf][nf][r];
        }
}

// ---------------- epilogue: reduce split-K, s@W3, activations, blend --------
__global__ void epilogue(const float* __restrict__ st0, const float* __restrict__ st1,
                         const float* __restrict__ b1, const float* __restrict__ b2,
                         const float* __restrict__ W3, const float* __restrict__ Mpart,
                         float* __restrict__ out) {
    const int tid = threadIdx.x;
    const int h = tid & 127, rg = tid >> 7;          // rg in {0,1}
    const int bbase = blockIdx.x * 8;                // 8 rows per block
    __shared__ float srow[8][256];
    #pragma unroll
    for (int i = 0; i < 8; ++i) {
        int idx = i * 256 + tid;
        int r = idx >> 8, j = idx & 255;
        float v = (j < 128) ? st0[(size_t)(bbase + r) * 128 + j]
                            : st1[(size_t)(bbase + r) * 128 + (j - 128)];
        srow[r][j] = v;
    }
    __syncthreads();
    float acc0 = 0.f, acc1 = 0.f, acc2 = 0.f, acc3 = 0.f;
    for (int j = 0; j < 256; ++j) {
        float w = W3[j * 128 + h];
        acc0 += srow[rg][j] * w;
        acc1 += srow[rg + 2][j] * w;
        acc2 += srow[rg + 4][j] * w;
        acc3 += srow[rg + 6][j] * w;
    }
    float accs[4] = {acc0, acc1, acc2, acc3};
    float bb1 = b1[h], bb2 = b2[h];
    #pragma unroll
    for (int i = 0; i < 4; ++i) {
        int b = bbase + rg + i * 2;
        float m1 = 0.f, m2 = 0.f;
        #pragma unroll
        for (int k = 0; k < 8; ++k) {
            m1 += Mpart[((size_t)k << 20) + (size_t)b * 256 + h];
            m2 += Mpart[((size_t)k << 20) + (size_t)b * 256 + 128 + h];
        }
        float u = 1.0f / (1.0f + expf(-(m2 + bb2)));
        float t = tanhf(m1 + bb1);
        out[(size_t)b * 128 + h] = u * t + (1.0f - u) * accs[i];
    }
}

extern "C" void kernel_launch(void* const* d_in, const int* in_sizes, int n_in,
                              void* d_out, int out_size, void* d_ws, size_t ws_size,
                              hipStream_t stream) {
    const float* in0 = (const float*)d_in[0];
    const float* in1 = (const float*)d_in[1];
    const float* st0 = (const float*)d_in[2];
    const float* st1 = (const float*)d_in[3];
    const float* W1  = (const float*)d_in[4];
    const float* b1  = (const float*)d_in[5];
    const float* W2  = (const float*)d_in[6];
    const float* b2  = (const float*)d_in[7];
    const float* W3  = (const float*)d_in[8];
    float* out = (float*)d_out;
    char* ws = (char*)d_ws;

    unsigned char* Wt   = (unsigned char*)(ws + WT_OFF);
    unsigned*      x_bf = (unsigned*)(ws + XBF_OFF);
    float*         Mp   = (float*)(ws + MP_OFF);

    prep_wx<<<9216, 256, 0, stream>>>(W1, W2, in0, in1, (unsigned*)Wt, x_bf);
    gemm_p<<<512, 256, 0, stream>>>(Wt, st0, st1, (const __hip_bfloat16*)x_bf, Mp);
    epilogue<<<512, 256, 0, stream>>>(st0, st1, b1, b2, W3, Mp, out);
}

// Round 9
// 258.173 us; speedup vs baseline: 57.2000x; 1.0308x over previous
//
#include <hip/hip_runtime.h>
#include <hip/hip_bf16.h>
#include <stdint.h>

// ---------------------------------------------------------------------------
// TensorizedGRU: m[b,l] = sum_{j,k} s[b,j] x[b,k] W[l,j,k]  (l in [0,256): W1||W2)
// R9 = R8 gemm (139.7us, MfmaUtil 44.5%) + coalesced fragment-order producer:
//  - prep: ONE WAVE produces ONE 1KB Wt fragment. Lane l reads
//    W[n16*16+(l&15)][kc*64+kst*32+(l>>4)*8 ..+8) (two float4; 128B-contig
//    per source row), packs bf16, writes Wt + f*1024 + l*16 -> contiguous
//    1KB wave-store. R8's producer scattered 16B writes at 256B stride
//    (~110us); this is fully coalesced.
//  - gemm_p/epilogue identical to R8.
// ws layout:
//   Wt   bf16 [256][65536]  @ 0          (33,554,432 B)  fragment-ordered
//   x_bf bf16 [4096][256]   @ 32MiB+2MiB ( 2,097,152 B)
//   Mpart f32 [8][4096][256]@ +2MiB      (33,554,432 B)
// ---------------------------------------------------------------------------

typedef short bf8 __attribute__((ext_vector_type(8)));   // 8 bf16 = 4 VGPRs
typedef float f32x4 __attribute__((ext_vector_type(4)));

static constexpr size_t WT_OFF  = 0;
static constexpr size_t XBF_OFF = 33554432 + 2097152;
static constexpr size_t MP_OFF  = XBF_OFF + 2097152;

// round-to-nearest-even f32 -> bf16 (finite inputs only)
__device__ __forceinline__ unsigned f2bf(float f) {
    unsigned u = __builtin_bit_cast(unsigned, f);
    return (u + 0x7fffu + ((u >> 16) & 1u)) >> 16;
}
__device__ __forceinline__ unsigned pack2bf(float a, float b) {
    return f2bf(a) | (f2bf(b) << 16);
}

// ---------------- prep: fragment-ordered Wt (wave-per-frag) + x cast --------
// Fragment f = ((n16*1024 + kchunk)*2 + kst), f in [0, 32768).
// Blocks 0..8191: 4 waves/block, wave w makes frag f = bx*4 + w.
// Blocks 8192..9215: x = in0||in1 -> bf16 (as R8).
__global__ void prep_wx(const float* __restrict__ W1, const float* __restrict__ W2,
                        const float* __restrict__ in0, const float* __restrict__ in1,
                        uint4* __restrict__ Wt, unsigned* __restrict__ x_bf) {
    int bx = blockIdx.x;
    if (bx < 8192) {
        const int tid  = threadIdx.x;
        const int lane = tid & 63, wave = tid >> 6;
        const unsigned f = bx * 4 + wave;
        const unsigned n16 = f >> 11;
        const unsigned kchunk = (f >> 1) & 1023u;
        const unsigned kst = f & 1u;
        const unsigned n = n16 * 16 + (lane & 15);
        const unsigned K = kchunk * 64 + kst * 32 + (lane >> 4) * 8;
        const float* src = (n < 128 ? W1 + ((size_t)n << 16)
                                    : W2 + ((size_t)(n - 128) << 16)) + K;
        float4 a = ((const float4*)src)[0];
        float4 b = ((const float4*)src)[1];
        uint4 o;
        o.x = pack2bf(a.x, a.y); o.y = pack2bf(a.z, a.w);
        o.z = pack2bf(b.x, b.y); o.w = pack2bf(b.z, b.w);
        Wt[(size_t)f * 64 + lane] = o;        // contiguous 1KB per wave
    } else {
        unsigned v = (bx - 8192) * 256 + threadIdx.x; // 262,144 units of 4 elems
        unsigned b = v >> 6;
        unsigned j4 = (v & 63u) * 4u;
        const float* src = (j4 < 128) ? (in0 + (size_t)b * 128 + j4)
                                      : (in1 + (size_t)b * 128 + (j4 - 128));
        float4 a = *(const float4*)src;
        uint2 o;
        o.x = pack2bf(a.x, a.y);
        o.y = pack2bf(a.z, a.w);
        ((uint2*)x_bf)[v] = o;
    }
}

// ---------------- main GEMM: 128x128 tile, split-K=8, barrier-free ----------
// grid 512: ks = bx&7 (XCD-pinned), nt = (bx>>3)&1, mt = bx>>4 (0..31).
// block 256 = 4 waves; wave w owns n-cols [w*32, w*32+32), all 128 m-rows.
__launch_bounds__(256, 2)
__global__ void gemm_p(const unsigned char* __restrict__ Wt,
                       const float* __restrict__ st0, const float* __restrict__ st1,
                       const __hip_bfloat16* __restrict__ x_bf,
                       float* __restrict__ Mpart) {
    const int bx = blockIdx.x;
    const int ks = bx & 7;                  // split-K slice, pinned per XCD
    const int nt = (bx >> 3) & 1;
    const int mt = bx >> 4;
    const int b0 = mt << 7, n0 = nt << 7;
    const int tid  = threadIdx.x;
    const int lane = tid & 63, wave = tid >> 6;
    const int l15 = lane & 15, l4 = lane >> 4;

    // s tile: [32 j][132 r] f32 (pad to 132 -> broadcast-clean)
    __shared__ __align__(16) float Sl[32 * 132];
    for (int idx = tid; idx < 4096; idx += 256) {
        int r = idx >> 5, j = idx & 31;
        int jg = ks * 32 + j;
        float v = (jg < 128) ? st0[(size_t)(b0 + r) * 128 + jg]
                             : st1[(size_t)(b0 + r) * 128 + (jg - 128)];
        Sl[j * 132 + r] = v;
    }
    __syncthreads();                        // the ONLY barrier

    // B-frag bases, fragment-ordered Wt:
    // n16(nf) = nt*8 + wave*2 + nf; frag addr = ((n16*1024 + kchunk)*2+kst)*1024 + lane*16
    const unsigned char* rbn[2];
    #pragma unroll
    for (int nf = 0; nf < 2; ++nf)
        rbn[nf] = Wt + ((size_t)(nt * 8 + wave * 2 + nf) << 21) + lane * 16;
    const float* sB = Sl + l4 * 4;

    f32x4 racc[8][2];
    #pragma unroll
    for (int mf = 0; mf < 8; ++mf)
        #pragma unroll
        for (int nf = 0; nf < 2; ++nf)
            racc[mf][nf] = (f32x4){0.f, 0.f, 0.f, 0.f};
    const f32x4 zacc = (f32x4){0.f, 0.f, 0.f, 0.f};

    // chunk c in [0,128): q = c>>5 (x-quadrant), j = c&31 (local j)
    // kchunk(c) = ((ks*32 + j)*4 + q); byte offset = kchunk*2048 (+ kst*1024)
    auto kof = [&](int c) { return (size_t)(((ks * 32 + (c & 31)) * 4 + (c >> 5)) * 2048); };

    bf8 buf[2][2][2];                       // [ping][nf][kst]
    #pragma unroll
    for (int nf = 0; nf < 2; ++nf)
        #pragma unroll
        for (int kst = 0; kst < 2; ++kst)
            buf[0][nf][kst] = *(const bf8*)(rbn[nf] + kof(0) + kst * 1024);

    bf8 a[8][2];                            // x A-frags, reloaded at q boundary

    #pragma unroll 2
    for (int c = 0; c < 128; ++c) {
        const int pp = c & 1;
        const int q = c >> 5, j = c & 31;
        if (j == 0) {                       // new x-quadrant: reload A-frags
            const __hip_bfloat16* xb = x_bf + q * 64 + l4 * 8;
            #pragma unroll
            for (int mf = 0; mf < 8; ++mf)
                #pragma unroll
                for (int kst = 0; kst < 2; ++kst)
                    a[mf][kst] = *(const bf8*)(xb + (size_t)(b0 + mf * 16 + l15) * 256 + kst * 32);
        }
        // prefetch next chunk's B-frags (wraps to 0 on last iter: harmless)
        {
            const size_t k1 = kof((c + 1) & 127);
            #pragma unroll
            for (int nf = 0; nf < 2; ++nf)
                #pragma unroll
                for (int kst = 0; kst < 2; ++kst)
                    buf[pp ^ 1][nf][kst] = *(const bf8*)(rbn[nf] + k1 + kst * 1024);
        }
        // s broadcast values for this j
        f32x4 sv[8];
        #pragma unroll
        for (int mf = 0; mf < 8; ++mf)
            sv[mf] = *(const f32x4*)(sB + j * 132 + mf * 16);
        // 32 MFMA + f32 scale-accumulate
        #pragma unroll
        for (int nf = 0; nf < 2; ++nf) {
            bf8 bf0 = buf[pp][nf][0];
            bf8 bf1 = buf[pp][nf][1];
            #pragma unroll
            for (int mf = 0; mf < 8; ++mf) {
                f32x4 m0 = __builtin_amdgcn_mfma_f32_16x16x32_bf16(a[mf][0], bf0, zacc, 0, 0, 0);
                m0 = __builtin_amdgcn_mfma_f32_16x16x32_bf16(a[mf][1], bf1, m0, 0, 0, 0);
                racc[mf][nf] += sv[mf] * m0;
            }
        }
    }

    // split-K partial stores (regular stores: producer->consumer coherence)
    float* mp = Mpart + ((size_t)ks << 20);
    #pragma unroll
    for (int mf = 0; mf < 8; ++mf)
        #pragma unroll
        for (int nf = 0; nf < 2; ++nf) {
            int b = b0 + mf * 16 + l4 * 4;
            int n = n0 + wave * 32 + nf * 16 + l15;
            #pragma unroll
            for (int r = 0; r < 4; ++r)
                mp[(size_t)(b + r) * 256 + n] = racc[mf][nf][r];
        }
}

// ---------------- epilogue: reduce split-K, s@W3, activations, blend --------
__global__ void epilogue(const float* __restrict__ st0, const float* __restrict__ st1,
                         const float* __restrict__ b1, const float* __restrict__ b2,
                         const float* __restrict__ W3, const float* __restrict__ Mpart,
                         float* __restrict__ out) {
    const int tid = threadIdx.x;
    const int h = tid & 127, rg = tid >> 7;          // rg in {0,1}
    const int bbase = blockIdx.x * 8;                // 8 rows per block
    __shared__ float srow[8][256];
    #pragma unroll
    for (int i = 0; i < 8; ++i) {
        int idx = i * 256 + tid;
        int r = idx >> 8, j = idx & 255;
        float v = (j < 128) ? st0[(size_t)(bbase + r) * 128 + j]
                            : st1[(size_t)(bbase + r) * 128 + (j - 128)];
        srow[r][j] = v;
    }
    __syncthreads();
    float acc0 = 0.f, acc1 = 0.f, acc2 = 0.f, acc3 = 0.f;
    for (int j = 0; j < 256; ++j) {
        float w = W3[j * 128 + h];
        acc0 += srow[rg][j] * w;
        acc1 += srow[rg + 2][j] * w;
        acc2 += srow[rg + 4][j] * w;
        acc3 += srow[rg + 6][j] * w;
    }
    float accs[4] = {acc0, acc1, acc2, acc3};
    float bb1 = b1[h], bb2 = b2[h];
    #pragma unroll
    for (int i = 0; i < 4; ++i) {
        int b = bbase + rg + i * 2;
        float m1 = 0.f, m2 = 0.f;
        #pragma unroll
        for (int k = 0; k < 8; ++k) {
            m1 += Mpart[((size_t)k << 20) + (size_t)b * 256 + h];
            m2 += Mpart[((size_t)k << 20) + (size_t)b * 256 + 128 + h];
        }
        float u = 1.0f / (1.0f + expf(-(m2 + bb2)));
        float t = tanhf(m1 + bb1);
        out[(size_t)b * 128 + h] = u * t + (1.0f - u) * accs[i];
    }
}

extern "C" void kernel_launch(void* const* d_in, const int* in_sizes, int n_in,
                              void* d_out, int out_size, void* d_ws, size_t ws_size,
                              hipStream_t stream) {
    const float* in0 = (const float*)d_in[0];
    const float* in1 = (const float*)d_in[1];
    const float* st0 = (const float*)d_in[2];
    const float* st1 = (const float*)d_in[3];
    const float* W1  = (const float*)d_in[4];
    const float* b1  = (const float*)d_in[5];
    const float* W2  = (const float*)d_in[6];
    const float* b2  = (const float*)d_in[7];
    const float* W3  = (const float*)d_in[8];
    float* out = (float*)d_out;
    char* ws = (char*)d_ws;

    unsigned char* Wt   = (unsigned char*)(ws + WT_OFF);
    unsigned*      x_bf = (unsigned*)(ws + XBF_OFF);
    float*         Mp   = (float*)(ws + MP_OFF);

    prep_wx<<<9216, 256, 0, stream>>>(W1, W2, in0, in1, (uint4*)Wt, x_bf);
    gemm_p<<<512, 256, 0, stream>>>(Wt, st0, st1, (const __hip_bfloat16*)x_bf, Mp);
    epilogue<<<512, 256, 0, stream>>>(st0, st1, b1, b2, W3, Mp, out);
}